// Round 18
// baseline (309.848 us; speedup 1.0000x reference)
//
#include <hip/hip_runtime.h>
#include <hip/hip_fp16.h>

typedef _Float16 f16;
typedef _Float16 f16x8 __attribute__((ext_vector_type(8)));
typedef _Float16 f16x4 __attribute__((ext_vector_type(4)));
typedef float    f32x4 __attribute__((ext_vector_type(4)));

#define SEQ      4096
#define DEMB     2048
#define SCALE_QK 0.08838834764831845f   // 1/sqrt(128)

#define GAS __attribute__((address_space(1)))
#define LAS __attribute__((address_space(3)))

__device__ __forceinline__ void load_lds16(const f16* g, f16* l) {
    __builtin_amdgcn_global_load_lds((const GAS void*)g, (LAS void*)l, 16, 0, 0);
}

// Swizzled LDS read: 16B slot (bits 4-6) ^= row&7 (bits 7-9). Verified R3:
// bank conflicts -> 0 for the 16x16 fragment pattern (16 rows x 4 k-slots).
// NOTE R13: the 32x32 pattern is NOT conflict-free under this swizzle.
__device__ __forceinline__ f16x8 ldsr(const f16* base, int byteoff) {
    byteoff ^= (byteoff >> 3) & 0x70;
    return *(const f16x8*)((const char*)base + byteoff);
}

// Stage one half-tile [128 rows][64 f16] into LDS: linear dest,
// inverse-swizzled per-lane source (rule #21). 512 threads, 2 issues.
__device__ __forceinline__ void stage_half(const f16* __restrict__ src, int ldk,
                                           f16* ldsdst, int tid) {
#pragma unroll
    for (int s = 0; s < 2; ++s) {
        const int o   = s * 8192 + tid * 16;
        const int osw = o ^ ((o >> 3) & 0x70);
        load_lds16(src + (size_t)(osw >> 7) * ldk + ((osw & 127) >> 1),
                   ldsdst + (s * 8192 + (tid >> 6) * 1024) / 2);
    }
}

// ---------------------------------------------------------------------------
// 256x256-tile GEMM core, BK=64, 8 waves (2Mx4N), 16x16x32 f16 MFMA.
// R18: 4 merged phases/iter (was 8) -> half the barriers; 32-MFMA clusters.
// WAR ledger: every region overwrite is one barrier after its last read
// (A0,B0,B1: read mph1 / write mph2; A1: read mph2 / write mph3; buf1 sym).
// RAW ledger: VM3 at mph2/mph4 -> each staged half lands >=2 barriers before
// its first read. Prologue VM3 (all 4 buf0 halves landed).
// MODE 0: f16 out = acc + bias[col]
// MODE 1: f16 transposed store (no bias)
// MODE 2: f32: bias ? direct+bias : partial store at row-roff
// MODE 3: f16 out = acc * scale
// ---------------------------------------------------------------------------
template <int MODE>
__device__ __forceinline__ void gemm_core(
        const f16* __restrict__ A, int lda, const f16* __restrict__ BT, int ldb,
        void* __restrict__ outp, int ldo, const float* __restrict__ bias,
        int bm, int bn, int NI, int kt0, float scale, f16* lds, int roff) {
    const int m0 = bm * 256, n0 = bn * 256;

    const int tid  = threadIdx.x;
    const int lane = tid & 63;
    const int wr   = (tid >> 6) >> 2;
    const int wc   = (tid >> 6) & 3;
    const int fr   = lane & 15;
    const int kb   = (lane >> 4) * 16;

    const f16* Abase = A + (size_t)m0 * lda + kt0 * 64;
    const f16* Bbase = BT + (size_t)n0 * ldb + kt0 * 64;

#define STG(buf, isB, half, t) \
    stage_half((isB) ? (Bbase + (size_t)((half) * 128) * ldb + (t) * 64) \
                     : (Abase + (size_t)((half) * 128) * lda + (t) * 64), \
               (isB) ? ldb : lda, \
               lds + (buf) * 32768 + (isB) * 16384 + (half) * 8192, tid)

    f32x4 acc[8][4] = {};
    f16x8 af[8], bf0[4], bf1[4];

#define READ_A(Mh, buf) { \
    const f16* bb = lds + (buf) * 32768; \
    _Pragma("unroll") for (int m = 0; m < 4; ++m) \
    _Pragma("unroll") for (int ks = 0; ks < 2; ++ks) \
        af[m * 2 + ks] = ldsr(bb, ((Mh) * 128 + wr * 64 + m * 16 + fr) * 128 + ks * 64 + kb); }

#define READ_B(Nh, buf, dst) { \
    const f16* bb = lds + (buf) * 32768 + 16384; \
    _Pragma("unroll") for (int n = 0; n < 2; ++n) \
    _Pragma("unroll") for (int ks = 0; ks < 2; ++ks) \
        dst[n * 2 + ks] = ldsr(bb, ((Nh) * 128 + wc * 32 + n * 16 + fr) * 128 + ks * 64 + kb); }

// Merged cluster: both N-halves for one M-half (32 MFMA) in one setprio region.
#define MFMA2(Mh) { \
    __builtin_amdgcn_s_setprio(1); \
    _Pragma("unroll") for (int m = 0; m < 4; ++m) \
    _Pragma("unroll") for (int n = 0; n < 2; ++n) \
    _Pragma("unroll") for (int ks = 0; ks < 2; ++ks) \
        acc[(Mh) * 4 + m][n] = __builtin_amdgcn_mfma_f32_16x16x32_f16( \
            af[m * 2 + ks], bf0[n * 2 + ks], acc[(Mh) * 4 + m][n], 0, 0, 0); \
    _Pragma("unroll") for (int m = 0; m < 4; ++m) \
    _Pragma("unroll") for (int n = 0; n < 2; ++n) \
    _Pragma("unroll") for (int ks = 0; ks < 2; ++ks) \
        acc[(Mh) * 4 + m][2 + n] = __builtin_amdgcn_mfma_f32_16x16x32_f16( \
            af[m * 2 + ks], bf1[n * 2 + ks], acc[(Mh) * 4 + m][2 + n], 0, 0, 0); \
    __builtin_amdgcn_s_setprio(0); }

#define BAR   asm volatile("s_barrier" ::: "memory")
#define VM3   asm volatile("s_waitcnt vmcnt(3)" ::: "memory")
#define VM0   asm volatile("s_waitcnt vmcnt(0)" ::: "memory")

    STG(0, 0, 0, 0); STG(0, 1, 0, 0); STG(0, 1, 1, 0); STG(0, 0, 1, 0);
    STG(1, 0, 0, 1); STG(1, 1, 0, 1); STG(1, 1, 1, 1);
    VM3; BAR;

    for (int i = 0; i < NI; ++i) {
        const int t0 = 2 * i;
        const bool more = (i + 1 < NI);
        // mph1: buf0 reads A0,B0,B1; stage buf1.A1 <- t0+1
        READ_A(0, 0); READ_B(0, 0, bf0); READ_B(1, 0, bf1);
        STG(1, 0, 1, t0 + 1);
        BAR; MFMA2(0); BAR;
        // mph2: buf0 reads A1; stage buf0.{A0,B0,B1} <- t0+2; VM3 (VM0 last)
        READ_A(1, 0);
        if (more) {
            STG(0, 0, 0, t0 + 2); STG(0, 1, 0, t0 + 2); STG(0, 1, 1, t0 + 2);
            VM3;
        } else {
            VM0;
        }
        BAR; MFMA2(1); BAR;
        // mph3: buf1 reads A0,B0,B1; stage buf0.A1 <- t0+2
        READ_A(0, 1); READ_B(0, 1, bf0); READ_B(1, 1, bf1);
        if (more) STG(0, 0, 1, t0 + 2);
        BAR; MFMA2(0); BAR;
        // mph4: buf1 reads A1; stage buf1.{A0,B0,B1} <- t0+3; VM3
        READ_A(1, 1);
        if (more) {
            STG(1, 0, 0, t0 + 3); STG(1, 1, 0, t0 + 3); STG(1, 1, 1, t0 + 3);
        }
        VM3;
        BAR; MFMA2(1); BAR;
    }

    const int rq = (lane >> 4) * 4;
#pragma unroll
    for (int mi = 0; mi < 8; ++mi) {
        const int row = m0 + (mi >> 2) * 128 + wr * 64 + (mi & 3) * 16 + rq;
#pragma unroll
        for (int ni = 0; ni < 4; ++ni) {
            const int col = n0 + (ni >> 1) * 128 + wc * 32 + (ni & 1) * 16 + fr;
            if (MODE == 0) {
                f16* o = (f16*)outp;
                const float bv = bias[col];
#pragma unroll
                for (int r = 0; r < 4; ++r)
                    o[(size_t)(row + r) * ldo + col] = (f16)(acc[mi][ni][r] + bv);
            } else if (MODE == 1) {
                f16* o = (f16*)outp;
                f16x4 v;
#pragma unroll
                for (int r = 0; r < 4; ++r) v[r] = (f16)acc[mi][ni][r];
                *(f16x4*)&o[(size_t)col * ldo + row] = v;
            } else if (MODE == 2) {
                float* o = (float*)outp;
                if (bias) {
                    const float bv = bias[col];
#pragma unroll
                    for (int r = 0; r < 4; ++r)
                        o[(size_t)(row + r) * ldo + col] = acc[mi][ni][r] + bv;
                } else {
#pragma unroll
                    for (int r = 0; r < 4; ++r)
                        o[(size_t)(row - roff + r) * ldo + col] = acc[mi][ni][r];
                }
            } else {
                f16* o = (f16*)outp;
#pragma unroll
                for (int r = 0; r < 4; ++r)
                    o[(size_t)(row + r) * ldo + col] = (f16)(acc[mi][ni][r] * scale);
            }
        }
    }
#undef STG
#undef READ_A
#undef READ_B
#undef MFMA2
#undef BAR
#undef VM3
#undef VM0
}

// ---------------------------------------------------------------------------
// Fused prep (one launch): bid<8192 x->f16; <12288 WV->f16; <12292 bqk copy;
// <12294 bc=bO; >=12294 transpose W_Q/W_K/W_O (3x1024 tile-blocks).
__global__ __launch_bounds__(256) void k_prep(
        const float* __restrict__ x, const float* __restrict__ WV,
        const float* __restrict__ WQ, const float* __restrict__ WK,
        const float* __restrict__ WO,
        const float* __restrict__ bQ, const float* __restrict__ bK,
        const float* __restrict__ bO,
        f16* __restrict__ x16, f16* __restrict__ wv16,
        f16* __restrict__ wqkt, f16* __restrict__ wot,
        float* __restrict__ bqk, float* __restrict__ bc) {
    __shared__ f16 tile[64][72];
    const int bid = blockIdx.x;
    if (bid < 12288) {
        const bool isX = bid < 8192;
        const float* src = isX ? x : WV;
        f16* dst = isX ? x16 : wv16;
        const int i = (isX ? bid : bid - 8192) * 1024 + threadIdx.x * 4;
        float4 v = *(const float4*)&src[i];
        f16x4 o; o[0] = (f16)v.x; o[1] = (f16)v.y; o[2] = (f16)v.z; o[3] = (f16)v.w;
        *(f16x4*)&dst[i] = o;
        return;
    }
    if (bid < 12292) {
        const int i = (bid - 12288) * 1024 + threadIdx.x * 4;
        float4 v = (i < 2048) ? *(const float4*)&bQ[i]
                              : *(const float4*)&bK[i - 2048];
        *(float4*)&bqk[i] = v;
        return;
    }
    if (bid < 12294) {
        const int i = (bid - 12292) * 1024 + threadIdx.x * 4;
        *(float4*)&bc[i] = *(const float4*)&bO[i];
        return;
    }
    // transpose+convert: b in [0, 3072)
    const int b = bid - 12294;
    const int z = b >> 10;                   // 0:WQ 1:WK 2:WO
    const int rem = b & 1023;
    const float* in = z == 0 ? WQ : z == 1 ? WK : WO;
    f16* out = z == 0 ? wqkt : z == 1 ? wqkt + (size_t)DEMB * DEMB : wot;
    const int c0 = (rem & 31) * 64, r0 = (rem >> 5) * 64;
    const int tx = threadIdx.x & 63, ty = threadIdx.x >> 6;
    for (int rr = ty; rr < 64; rr += 4)
        tile[tx][rr] = (f16)in[(size_t)(r0 + rr) * DEMB + c0 + tx];
    __syncthreads();
    for (int cc = ty; cc < 64; cc += 4)
        out[(size_t)(c0 + cc) * DEMB + r0 + tx] = tile[cc][tx];
}

// Round 1 (256 blocks): bid<128 -> QK rows 0-2047 (bm 0-7);
//   bid in [128,192) -> W_VO^T = (W_V@W_O)^T;  bid>=192 -> bc partials.
__global__ __launch_bounds__(512, 2)
void k_mix1(const f16* __restrict__ x16, const f16* __restrict__ wqkt,
            f16* __restrict__ qk16, const float* __restrict__ bqk,
            const f16* __restrict__ wv16, const f16* __restrict__ wot,
            f16* __restrict__ wvoT, const float* __restrict__ WO,
            const float* __restrict__ bV, float* __restrict__ bc) {
    __shared__ f16 lds[65536];
    const int bid = blockIdx.x;
    if (bid < 128) {
        gemm_core<0>(x16, DEMB, wqkt, DEMB, qk16, 2 * DEMB, bqk,
                     bid >> 4, bid & 15, 16, 0, 1.f, lds, 0);
    } else if (bid < 192) {
        const int w = bid - 128;
        gemm_core<1>(wv16, DEMB, wot, DEMB, wvoT, DEMB, nullptr,
                     w >> 3, w & 7, 16, 0, 1.f, lds, 0);
    } else {
        const int b  = bid - 192;            // 64 blocks of bc partials
        const int j0 = (b & 7) * 256;
        const int i0 = (b >> 3) * 256 + (threadIdx.x >> 8) * 128;
        const int jj = threadIdx.x & 255;
        float acc = 0.f;
        for (int i = i0; i < i0 + 128; ++i)
            acc += bV[i] * WO[(size_t)i * DEMB + j0 + jj];
        atomicAdd(&bc[j0 + jj], acc);
    }
}

// Round 2 (256 blocks): bid<128 -> QK rows 2048-4095 (bm 8-15);
//   bid>=128 -> vwT = (x @ W_VO)^T  (wvoT produced by k_mix1).
__global__ __launch_bounds__(512, 2)
void k_mix2(const f16* __restrict__ x16, const f16* __restrict__ wqkt,
            f16* __restrict__ qk16, const float* __restrict__ bqk,
            const f16* __restrict__ wvoT, f16* __restrict__ vwT) {
    __shared__ f16 lds[65536];
    const int bid = blockIdx.x;
    if (bid < 128) {
        gemm_core<0>(x16, DEMB, wqkt, DEMB, qk16, 2 * DEMB, bqk,
                     8 + (bid >> 4), bid & 15, 16, 0, 1.f, lds, 0);
    } else {
        const int b = bid - 128;
        const int bmv = ((b & 7) << 1) | ((b >> 3) & 1);
        const int bnv = b >> 4;
        gemm_core<1>(x16, DEMB, wvoT, DEMB, vwT, SEQ, nullptr,
                     bmv, bnv, 16, 0, 1.f, lds, 0);
    }
}

// scores (triangular, 136 blocks): Q @ K^T * scale -> sb  (XCD-chunked ids)
__global__ __launch_bounds__(512, 2)
void k_scores(const f16* __restrict__ qk16, f16* __restrict__ sb) {
    __shared__ f16 lds[65536];
    const int l = blockIdx.x;
    const int bid = (l & 7) * 17 + (l >> 3);   // bijective on [0,136)
    int bm = (int)((sqrtf(8.f * bid + 1.f) - 1.f) * 0.5f);
    while ((bm + 1) * (bm + 2) / 2 <= bid) ++bm;
    while (bm * (bm + 1) / 2 > bid) --bm;
    const int bn = bid - bm * (bm + 1) / 2;
    gemm_core<3>(qk16, 2 * DEMB, qk16 + DEMB, 2 * DEMB, sb, SEQ, nullptr,
                 bm, bn, 16, 0, SCALE_QK, lds, 0);
}

// Causal row softmax, one row per 256-thread block, small LDS (8.25 KB) so
// ~8 blocks/CU co-reside. Exp computed once (cached in srow); pass 3 scales.
__global__ __launch_bounds__(256) void k_softmax(f16* __restrict__ sb) {
    __shared__ f16 srow[SEQ];
    __shared__ float red[8];
    const int i  = blockIdx.x;
    const int L  = i + 1;
    const int Lp = ((i >> 8) + 1) << 8;      // roundup(L,256) for PVW tiles
    f16* row = sb + (size_t)i * SEQ;
    const int t = threadIdx.x;

    float mx = -3.0e38f;
    for (int j0 = t * 8; j0 < Lp; j0 += 2048) {
        f16x8 v = *(const f16x8*)&row[j0];
        *(f16x8*)&srow[j0] = v;
#pragma unroll
        for (int u = 0; u < 8; ++u)
            if (j0 + u < L) mx = fmaxf(mx, (float)v[u]);
    }
#pragma unroll
    for (int o = 32; o > 0; o >>= 1) mx = fmaxf(mx, __shfl_xor(mx, o));
    if ((t & 63) == 0) red[t >> 6] = mx;
    __syncthreads();
    mx = fmaxf(fmaxf(red[0], red[1]), fmaxf(red[2], red[3]));

    float sm = 0.f;
    for (int j0 = t * 8; j0 < Lp; j0 += 2048) {
        f16x8 v = *(const f16x8*)&srow[j0];
        f16x8 e;
#pragma unroll
        for (int u = 0; u < 8; ++u) {
            const float ev = (j0 + u < L) ? __expf((float)v[u] - mx) : 0.f;
            sm += ev;
            e[u] = (f16)ev;
        }
        *(f16x8*)&srow[j0] = e;              // cache exp (own slice, no race)
    }
#pragma unroll
    for (int o = 32; o > 0; o >>= 1) sm += __shfl_xor(sm, o);
    if ((t & 63) == 0) red[4 + (t >> 6)] = sm;
    __syncthreads();
    const float inv = 1.f / (red[4] + red[5] + red[6] + red[7]);

    for (int j0 = t * 8; j0 < Lp; j0 += 2048) {
        f16x8 e = *(const f16x8*)&srow[j0];
        f16x8 wv;
#pragma unroll
        for (int u = 0; u < 8; ++u)
            wv[u] = (f16)((float)e[u] * inv);
        *(f16x8*)&row[j0] = wv;
    }
}

// PVW: out = P @ VW + bc, f32, causal, balanced split-K chunk table
// (32 chunks x 8 = 256 blocks = one full round, max NI=11). No atomics:
// ord 0 stores out+bias; ord 1 -> part1 (rows 1280+); ord 2 -> part2 (2816+).
__global__ __launch_bounds__(512, 2)
void k_pvw(const f16* __restrict__ sb, const f16* __restrict__ vwT,
           float* __restrict__ out, const float* __restrict__ bc,
           float* __restrict__ part1, float* __restrict__ part2) {
    __shared__ f16 lds[65536];
    static const short BMt[32]  = {0,1,2,3,4, 5,5, 6,6, 7,7, 8,8, 9,9, 10,10,
                                   11,11,11, 12,12,12, 13,13,13, 14,14,14,
                                   15,15,15};
    static const short KT0t[32] = {0,0,0,0,0, 0,12, 0,14, 0,16, 0,18, 0,20,
                                   0,22, 0,16,32, 0,18,36, 0,20,38, 0,20,40,
                                   0,22,44};
    static const short NIt[32]  = {2,4,6,8,10, 6,6, 7,7, 8,8, 9,9, 10,10,
                                   11,11, 8,8,8, 9,9,8, 10,9,9, 10,10,10,
                                   11,11,10};
    static const short ORDt[32] = {0,0,0,0,0, 0,1, 0,1, 0,1, 0,1, 0,1, 0,1,
                                   0,1,2, 0,1,2, 0,1,2, 0,1,2, 0,1,2};
    const int bn = blockIdx.x, e = blockIdx.y;
    const int bm = BMt[e], kt0 = KT0t[e], ni = NIt[e], ord = ORDt[e];
    float* op = ord == 0 ? out : ord == 1 ? part1 : part2;
    const int roff = ord == 1 ? 1280 : 2816;
    gemm_core<2>(sb, SEQ, vwT, SEQ, op, DEMB, ord == 0 ? bc : nullptr,
                 bm, bn, ni, kt0, 1.f, lds, roff);
}

// out[1280:] += part1 (+part2 for rows >= 2816). 5632 blocks x 256 thr.
__global__ __launch_bounds__(256) void k_reduce(
        float* __restrict__ out, const float* __restrict__ part1,
        const float* __restrict__ part2) {
    const int idx = (blockIdx.x * 256 + threadIdx.x) * 4;   // f32 idx in region
    float4 o = *(float4*)&out[(size_t)1280 * DEMB + idx];
    float4 p = *(const float4*)&part1[idx];
    o.x += p.x; o.y += p.y; o.z += p.z; o.w += p.w;
    if (idx >= 1536 * DEMB) {                               // row >= 2816
        float4 q = *(const float4*)&part2[idx - 1536 * DEMB];
        o.x += q.x; o.y += q.y; o.z += q.z; o.w += q.w;
    }
    *(float4*)&out[(size_t)1280 * DEMB + idx] = o;
}

// ---------------------------------------------------------------------------
extern "C" void kernel_launch(void* const* d_in, const int* in_sizes, int n_in,
                              void* d_out, int out_size, void* d_ws, size_t ws_size,
                              hipStream_t stream) {
    const float* x  = (const float*)d_in[0];
    const float* WQ = (const float*)d_in[1];
    const float* WK = (const float*)d_in[2];
    const float* WV = (const float*)d_in[3];
    const float* WO = (const float*)d_in[4];
    const float* bQ = (const float*)d_in[5];
    const float* bK = (const float*)d_in[6];
    const float* bV = (const float*)d_in[7];
    const float* bO = (const float*)d_in[8];
    float* out = (float*)d_out;

    // workspace (~126 MB); vwT aliases {wv16,wot};
    // part1 aliases qk16 (23.1 MB), part2 aliases wqkt (10.5 MB) - both dead.
    char* w = (char*)d_ws;
    f16* qk16 = (f16*)w; w += (size_t)SEQ * 2 * DEMB * 2;     // 33.5 MB
    f16* sb   = (f16*)w; w += (size_t)SEQ * SEQ * 2;          // 33.5 MB
    f16* x16  = (f16*)w; w += (size_t)SEQ * DEMB * 2;         // 16.8 MB
    f16* wqkt = (f16*)w; w += (size_t)2 * DEMB * DEMB * 2;    // 16.8 MB
    f16* wv16 = (f16*)w; w += (size_t)DEMB * DEMB * 2;        //  8.4 MB
    f16* wot  = (f16*)w; w += (size_t)DEMB * DEMB * 2;        //  8.4 MB
    f16* wvoT = (f16*)w; w += (size_t)DEMB * DEMB * 2;        //  8.4 MB
    float* bqk = (float*)w; w += 2 * DEMB * 4;                // 16 KB
    float* bc  = (float*)w; w += DEMB * 4 + 4096;             //  8 KB
    f16* vwT = wv16;                    // [2048][4096], spans wv16+wot
    float* part1 = (float*)qk16;        // rows 1280+: 2816x2048 f32 = 23.1 MB
    float* part2 = (float*)wqkt;        // rows 2816+: 1280x2048 f32 = 10.5 MB

    // prep: cvt + bias copies + weight transposes, one launch
    k_prep<<<15366, 256, 0, stream>>>(x, WV, WQ, WK, WO, bQ, bK, bO,
                                      x16, wv16, wqkt, wot, bqk, bc);

    // Round 1: QK(bm0-7) + WVO + bias partials = 256 blocks
    k_mix1<<<256, 512, 0, stream>>>(x16, wqkt, qk16, bqk, wv16, wot, wvoT,
                                    WO, bV, bc);

    // Round 2: QK(bm8-15) + VW = 256 blocks
    k_mix2<<<256, 512, 0, stream>>>(x16, wqkt, qk16, bqk, wvoT, vwT);

    // scores (triangular, XCD-chunked)
    k_scores<<<136, 512, 0, stream>>>(qk16, sb);

    // softmax: 4096 blocks, small LDS, ~8 blocks/CU, exp cached in LDS
    k_softmax<<<SEQ, 256, 0, stream>>>(sb);

    // PVW: balanced split-K, 32 chunks x 8 = 256 blocks, no atomics
    k_pvw<<<dim3(8, 32), 512, 0, stream>>>(sb, vwT, out, bc, part1, part2);

    // fold partials into rows 1280+
    k_reduce<<<5632, 256, 0, stream>>>(out, part1, part2);
}

// Round 19
// 278.316 us; speedup vs baseline: 1.1133x; 1.1133x over previous
//
#include <hip/hip_runtime.h>
#include <hip/hip_fp16.h>

typedef _Float16 f16;
typedef _Float16 f16x8 __attribute__((ext_vector_type(8)));
typedef _Float16 f16x4 __attribute__((ext_vector_type(4)));
typedef float    f32x4 __attribute__((ext_vector_type(4)));

#define SEQ      4096
#define DEMB     2048
#define SCALE_QK 0.08838834764831845f   // 1/sqrt(128)

#define GAS __attribute__((address_space(1)))
#define LAS __attribute__((address_space(3)))

__device__ __forceinline__ void load_lds16(const f16* g, f16* l) {
    __builtin_amdgcn_global_load_lds((const GAS void*)g, (LAS void*)l, 16, 0, 0);
}

// Swizzled LDS read: 16B slot (bits 4-6) ^= row&7 (bits 7-9). Verified R3:
// bank conflicts -> 0 for the 16x16 fragment pattern (16 rows x 4 k-slots).
// NOTE R13: the 32x32 pattern (32 rows x 2 k-slots) is NOT conflict-free
// under this swizzle (6.3M conflicts measured) - do not reintroduce.
// NOTE R18: merging to 4 phases/iter (fewer barriers, 32-MFMA clusters)
// REGRESSED 69->80us/block - the 8-phase fine interleave is the optimum.
__device__ __forceinline__ f16x8 ldsr(const f16* base, int byteoff) {
    byteoff ^= (byteoff >> 3) & 0x70;
    return *(const f16x8*)((const char*)base + byteoff);
}

// Stage one half-tile [128 rows][64 f16] into LDS: linear dest,
// inverse-swizzled per-lane source (rule #21). 512 threads, 2 issues.
__device__ __forceinline__ void stage_half(const f16* __restrict__ src, int ldk,
                                           f16* ldsdst, int tid) {
#pragma unroll
    for (int s = 0; s < 2; ++s) {
        const int o   = s * 8192 + tid * 16;
        const int osw = o ^ ((o >> 3) & 0x70);
        load_lds16(src + (size_t)(osw >> 7) * ldk + ((osw & 127) >> 1),
                   ldsdst + (s * 8192 + (tid >> 6) * 1024) / 2);
    }
}

// ---------------------------------------------------------------------------
// 256x256-tile 8-phase GEMM core (T2+T3+T4+T5), BK=64, 8 waves (2Mx4N),
// v_mfma_f32_16x16x32_f16 (R12 known-good core; R16 phase-waits null;
// R18 4-phase merge regressed - this 8-phase form is the defended optimum).
// NI = iterations (2 K-tiles of 64 each); kt0 = starting K-tile.
// MODE 0: f16 out[row*ldo+col] = acc + bias[col]
// MODE 1: f16 out[col*ldo+row] = acc              (transposed store, no bias)
// MODE 2: f32 store: bias ? out[row][col]=acc+bias[col]
//                         : out[(row-roff)][col]=acc   (split-K partial)
// MODE 3: f16 out[row*ldo+col] = acc * scale
// ---------------------------------------------------------------------------
template <int MODE>
__device__ __forceinline__ void gemm_core(
        const f16* __restrict__ A, int lda, const f16* __restrict__ BT, int ldb,
        void* __restrict__ outp, int ldo, const float* __restrict__ bias,
        int bm, int bn, int NI, int kt0, float scale, f16* lds, int roff) {
    const int m0 = bm * 256, n0 = bn * 256;

    const int tid  = threadIdx.x;
    const int lane = tid & 63;
    const int wr   = (tid >> 6) >> 2;
    const int wc   = (tid >> 6) & 3;
    const int fr   = lane & 15;
    const int kb   = (lane >> 4) * 16;

    const f16* Abase = A + (size_t)m0 * lda + kt0 * 64;
    const f16* Bbase = BT + (size_t)n0 * ldb + kt0 * 64;

#define STG(buf, isB, half, t) \
    stage_half((isB) ? (Bbase + (size_t)((half) * 128) * ldb + (t) * 64) \
                     : (Abase + (size_t)((half) * 128) * lda + (t) * 64), \
               (isB) ? ldb : lda, \
               lds + (buf) * 32768 + (isB) * 16384 + (half) * 8192, tid)

    f32x4 acc[8][4] = {};
    f16x8 af[8], bf0[4], bf1[4];

#define READ_A(Mh, buf) { \
    const f16* bb = lds + (buf) * 32768; \
    _Pragma("unroll") for (int m = 0; m < 4; ++m) \
    _Pragma("unroll") for (int ks = 0; ks < 2; ++ks) \
        af[m * 2 + ks] = ldsr(bb, ((Mh) * 128 + wr * 64 + m * 16 + fr) * 128 + ks * 64 + kb); }

#define READ_B(Nh, buf, dst) { \
    const f16* bb = lds + (buf) * 32768 + 16384; \
    _Pragma("unroll") for (int n = 0; n < 2; ++n) \
    _Pragma("unroll") for (int ks = 0; ks < 2; ++ks) \
        dst[n * 2 + ks] = ldsr(bb, ((Nh) * 128 + wc * 32 + n * 16 + fr) * 128 + ks * 64 + kb); }

#define MFMA_PH(Mh, Nh, bfx) { \
    __builtin_amdgcn_s_setprio(1); \
    _Pragma("unroll") for (int m = 0; m < 4; ++m) \
    _Pragma("unroll") for (int n = 0; n < 2; ++n) \
    _Pragma("unroll") for (int ks = 0; ks < 2; ++ks) \
        acc[(Mh) * 4 + m][(Nh) * 2 + n] = __builtin_amdgcn_mfma_f32_16x16x32_f16( \
            af[m * 2 + ks], bfx[n * 2 + ks], acc[(Mh) * 4 + m][(Nh) * 2 + n], 0, 0, 0); \
    __builtin_amdgcn_s_setprio(0); }

#define BAR   asm volatile("s_barrier" ::: "memory")
#define VM6   asm volatile("s_waitcnt vmcnt(6)" ::: "memory")
#define VM0   asm volatile("s_waitcnt vmcnt(0)" ::: "memory")

    STG(0, 0, 0, 0); STG(0, 1, 0, 0); STG(0, 1, 1, 0); STG(0, 0, 1, 0);
    STG(1, 0, 0, 1); STG(1, 1, 0, 1); STG(1, 1, 1, 1);
    VM6; BAR;

    for (int i = 0; i < NI; ++i) {
        const int t0 = 2 * i;
        const bool more = (i + 1 < NI);
        READ_A(0, 0); READ_B(0, 0, bf0);
        STG(1, 0, 1, t0 + 1);
        BAR; MFMA_PH(0, 0, bf0); BAR;
        READ_B(1, 0, bf1);
        if (more) STG(0, 0, 0, t0 + 2);
        BAR; MFMA_PH(0, 1, bf1); BAR;
        READ_A(1, 0);
        if (more) STG(0, 1, 0, t0 + 2);
        BAR; MFMA_PH(1, 0, bf0); BAR;
        if (more) { STG(0, 1, 1, t0 + 2); VM6; } else { VM0; }
        BAR; MFMA_PH(1, 1, bf1); BAR;
        READ_A(0, 1); READ_B(0, 1, bf0);
        if (more) STG(0, 0, 1, t0 + 2);
        BAR; MFMA_PH(0, 0, bf0); BAR;
        READ_B(1, 1, bf1);
        if (more) STG(1, 0, 0, t0 + 3);
        BAR; MFMA_PH(0, 1, bf1); BAR;
        READ_A(1, 1);
        if (more) STG(1, 1, 0, t0 + 3);
        BAR; MFMA_PH(1, 0, bf0); BAR;
        if (more) STG(1, 1, 1, t0 + 3);
        VM6;
        BAR; MFMA_PH(1, 1, bf1); BAR;
    }

    const int rq = (lane >> 4) * 4;
#pragma unroll
    for (int mi = 0; mi < 8; ++mi) {
        const int row = m0 + (mi >> 2) * 128 + wr * 64 + (mi & 3) * 16 + rq;
#pragma unroll
        for (int ni = 0; ni < 4; ++ni) {
            const int col = n0 + (ni >> 1) * 128 + wc * 32 + (ni & 1) * 16 + fr;
            if (MODE == 0) {
                f16* o = (f16*)outp;
                const float bv = bias[col];
#pragma unroll
                for (int r = 0; r < 4; ++r)
                    o[(size_t)(row + r) * ldo + col] = (f16)(acc[mi][ni][r] + bv);
            } else if (MODE == 1) {
                f16* o = (f16*)outp;
                f16x4 v;
#pragma unroll
                for (int r = 0; r < 4; ++r) v[r] = (f16)acc[mi][ni][r];
                *(f16x4*)&o[(size_t)col * ldo + row] = v;
            } else if (MODE == 2) {
                float* o = (float*)outp;
                if (bias) {
                    const float bv = bias[col];
#pragma unroll
                    for (int r = 0; r < 4; ++r)
                        o[(size_t)(row + r) * ldo + col] = acc[mi][ni][r] + bv;
                } else {
#pragma unroll
                    for (int r = 0; r < 4; ++r)
                        o[(size_t)(row - roff + r) * ldo + col] = acc[mi][ni][r];
                }
            } else {
                f16* o = (f16*)outp;
#pragma unroll
                for (int r = 0; r < 4; ++r)
                    o[(size_t)(row + r) * ldo + col] = (f16)(acc[mi][ni][r] * scale);
            }
        }
    }
#undef STG
#undef READ_A
#undef READ_B
#undef MFMA_PH
#undef BAR
#undef VM6
#undef VM0
}

// ---------------------------------------------------------------------------
// Fused prep (one launch): bid<8192 x->f16; <12288 WV->f16; <12292 bqk copy;
// <12294 bc=bO; >=12294 transpose W_Q/W_K/W_O (3x1024 tile-blocks).
__global__ __launch_bounds__(256) void k_prep(
        const float* __restrict__ x, const float* __restrict__ WV,
        const float* __restrict__ WQ, const float* __restrict__ WK,
        const float* __restrict__ WO,
        const float* __restrict__ bQ, const float* __restrict__ bK,
        const float* __restrict__ bO,
        f16* __restrict__ x16, f16* __restrict__ wv16,
        f16* __restrict__ wqkt, f16* __restrict__ wot,
        float* __restrict__ bqk, float* __restrict__ bc) {
    __shared__ f16 tile[64][72];
    const int bid = blockIdx.x;
    if (bid < 12288) {
        const bool isX = bid < 8192;
        const float* src = isX ? x : WV;
        f16* dst = isX ? x16 : wv16;
        const int i = (isX ? bid : bid - 8192) * 1024 + threadIdx.x * 4;
        float4 v = *(const float4*)&src[i];
        f16x4 o; o[0] = (f16)v.x; o[1] = (f16)v.y; o[2] = (f16)v.z; o[3] = (f16)v.w;
        *(f16x4*)&dst[i] = o;
        return;
    }
    if (bid < 12292) {
        const int i = (bid - 12288) * 1024 + threadIdx.x * 4;
        float4 v = (i < 2048) ? *(const float4*)&bQ[i]
                              : *(const float4*)&bK[i - 2048];
        *(float4*)&bqk[i] = v;
        return;
    }
    if (bid < 12294) {
        const int i = (bid - 12292) * 1024 + threadIdx.x * 4;
        *(float4*)&bc[i] = *(const float4*)&bO[i];
        return;
    }
    // transpose+convert: b in [0, 3072)
    const int b = bid - 12294;
    const int z = b >> 10;                   // 0:WQ 1:WK 2:WO
    const int rem = b & 1023;
    const float* in = z == 0 ? WQ : z == 1 ? WK : WO;
    f16* out = z == 0 ? wqkt : z == 1 ? wqkt + (size_t)DEMB * DEMB : wot;
    const int c0 = (rem & 31) * 64, r0 = (rem >> 5) * 64;
    const int tx = threadIdx.x & 63, ty = threadIdx.x >> 6;
    for (int rr = ty; rr < 64; rr += 4)
        tile[tx][rr] = (f16)in[(size_t)(r0 + rr) * DEMB + c0 + tx];
    __syncthreads();
    for (int cc = ty; cc < 64; cc += 4)
        out[(size_t)(c0 + cc) * DEMB + r0 + tx] = tile[cc][tx];
}

// Round 1 (256 blocks): bid<128 -> QK rows 0-2047 (bm 0-7);
//   bid in [128,192) -> W_VO^T = (W_V@W_O)^T;  bid>=192 -> bc partials.
__global__ __launch_bounds__(512, 2)
void k_mix1(const f16* __restrict__ x16, const f16* __restrict__ wqkt,
            f16* __restrict__ qk16, const float* __restrict__ bqk,
            const f16* __restrict__ wv16, const f16* __restrict__ wot,
            f16* __restrict__ wvoT, const float* __restrict__ WO,
            const float* __restrict__ bV, float* __restrict__ bc) {
    __shared__ f16 lds[65536];
    const int bid = blockIdx.x;
    if (bid < 128) {
        gemm_core<0>(x16, DEMB, wqkt, DEMB, qk16, 2 * DEMB, bqk,
                     bid >> 4, bid & 15, 16, 0, 1.f, lds, 0);
    } else if (bid < 192) {
        const int w = bid - 128;
        gemm_core<1>(wv16, DEMB, wot, DEMB, wvoT, DEMB, nullptr,
                     w >> 3, w & 7, 16, 0, 1.f, lds, 0);
    } else {
        const int b  = bid - 192;            // 64 blocks of bc partials
        const int j0 = (b & 7) * 256;
        const int i0 = (b >> 3) * 256 + (threadIdx.x >> 8) * 128;
        const int jj = threadIdx.x & 255;
        float acc = 0.f;
        for (int i = i0; i < i0 + 128; ++i)
            acc += bV[i] * WO[(size_t)i * DEMB + j0 + jj];
        atomicAdd(&bc[j0 + jj], acc);
    }
}

// Round 2 (256 blocks): bid<128 -> QK rows 2048-4095 (bm 8-15);
//   bid>=128 -> vwT = (x @ W_VO)^T  (wvoT produced by k_mix1).
__global__ __launch_bounds__(512, 2)
void k_mix2(const f16* __restrict__ x16, const f16* __restrict__ wqkt,
            f16* __restrict__ qk16, const float* __restrict__ bqk,
            const f16* __restrict__ wvoT, f16* __restrict__ vwT) {
    __shared__ f16 lds[65536];
    const int bid = blockIdx.x;
    if (bid < 128) {
        gemm_core<0>(x16, DEMB, wqkt, DEMB, qk16, 2 * DEMB, bqk,
                     8 + (bid >> 4), bid & 15, 16, 0, 1.f, lds, 0);
    } else {
        const int b = bid - 128;
        const int bmv = ((b & 7) << 1) | ((b >> 3) & 1);
        const int bnv = b >> 4;
        gemm_core<1>(x16, DEMB, wvoT, DEMB, vwT, SEQ, nullptr,
                     bmv, bnv, 16, 0, 1.f, lds, 0);
    }
}

// scores (triangular, 136 blocks): Q @ K^T * scale -> sb  (XCD-chunked ids)
__global__ __launch_bounds__(512, 2)
void k_scores(const f16* __restrict__ qk16, f16* __restrict__ sb) {
    __shared__ f16 lds[65536];
    const int l = blockIdx.x;
    const int bid = (l & 7) * 17 + (l >> 3);   // bijective on [0,136)
    int bm = (int)((sqrtf(8.f * bid + 1.f) - 1.f) * 0.5f);
    while ((bm + 1) * (bm + 2) / 2 <= bid) ++bm;
    while (bm * (bm + 1) / 2 > bid) --bm;
    const int bn = bid - bm * (bm + 1) / 2;
    gemm_core<3>(qk16, 2 * DEMB, qk16 + DEMB, 2 * DEMB, sb, SEQ, nullptr,
                 bm, bn, 16, 0, SCALE_QK, lds, 0);
}

// Causal row softmax, one row per 256-thread block, small LDS (8.25 KB) so
// ~8 blocks/CU co-reside. Exp computed once (cached in srow); pass 3 scales.
__global__ __launch_bounds__(256) void k_softmax(f16* __restrict__ sb) {
    __shared__ f16 srow[SEQ];
    __shared__ float red[8];
    const int i  = blockIdx.x;
    const int L  = i + 1;
    const int Lp = ((i >> 8) + 1) << 8;      // roundup(L,256) for PVW tiles
    f16* row = sb + (size_t)i * SEQ;
    const int t = threadIdx.x;

    float mx = -3.0e38f;
    for (int j0 = t * 8; j0 < Lp; j0 += 2048) {
        f16x8 v = *(const f16x8*)&row[j0];
        *(f16x8*)&srow[j0] = v;
#pragma unroll
        for (int u = 0; u < 8; ++u)
            if (j0 + u < L) mx = fmaxf(mx, (float)v[u]);
    }
#pragma unroll
    for (int o = 32; o > 0; o >>= 1) mx = fmaxf(mx, __shfl_xor(mx, o));
    if ((t & 63) == 0) red[t >> 6] = mx;
    __syncthreads();
    mx = fmaxf(fmaxf(red[0], red[1]), fmaxf(red[2], red[3]));

    float sm = 0.f;
    for (int j0 = t * 8; j0 < Lp; j0 += 2048) {
        f16x8 v = *(const f16x8*)&srow[j0];
        f16x8 e;
#pragma unroll
        for (int u = 0; u < 8; ++u) {
            const float ev = (j0 + u < L) ? __expf((float)v[u] - mx) : 0.f;
            sm += ev;
            e[u] = (f16)ev;
        }
        *(f16x8*)&srow[j0] = e;              // cache exp (own slice, no race)
    }
#pragma unroll
    for (int o = 32; o > 0; o >>= 1) sm += __shfl_xor(sm, o);
    if ((t & 63) == 0) red[4 + (t >> 6)] = sm;
    __syncthreads();
    const float inv = 1.f / (red[4] + red[5] + red[6] + red[7]);

    for (int j0 = t * 8; j0 < Lp; j0 += 2048) {
        f16x8 e = *(const f16x8*)&srow[j0];
        f16x8 wv;
#pragma unroll
        for (int u = 0; u < 8; ++u)
            wv[u] = (f16)((float)e[u] * inv);
        *(f16x8*)&row[j0] = wv;
    }
}

// PVW: out = P @ VW + bc, f32, causal, balanced split-K chunk table
// (32 chunks x 8 = 256 blocks = one full round, max NI=11). No atomics:
// ord 0 stores out+bias; ord 1 -> part1 (rows 1280+); ord 2 -> part2 (2816+).
__global__ __launch_bounds__(512, 2)
void k_pvw(const f16* __restrict__ sb, const f16* __restrict__ vwT,
           float* __restrict__ out, const float* __restrict__ bc,
           float* __restrict__ part1, float* __restrict__ part2) {
    __shared__ f16 lds[65536];
    static const short BMt[32]  = {0,1,2,3,4, 5,5, 6,6, 7,7, 8,8, 9,9, 10,10,
                                   11,11,11, 12,12,12, 13,13,13, 14,14,14,
                                   15,15,15};
    static const short KT0t[32] = {0,0,0,0,0, 0,12, 0,14, 0,16, 0,18, 0,20,
                                   0,22, 0,16,32, 0,18,36, 0,20,38, 0,20,40,
                                   0,22,44};
    static const short NIt[32]  = {2,4,6,8,10, 6,6, 7,7, 8,8, 9,9, 10,10,
                                   11,11, 8,8,8, 9,9,8, 10,9,9, 10,10,10,
                                   11,11,10};
    static const short ORDt[32] = {0,0,0,0,0, 0,1, 0,1, 0,1, 0,1, 0,1, 0,1,
                                   0,1,2, 0,1,2, 0,1,2, 0,1,2, 0,1,2};
    const int bn = blockIdx.x, e = blockIdx.y;
    const int bm = BMt[e], kt0 = KT0t[e], ni = NIt[e], ord = ORDt[e];
    float* op = ord == 0 ? out : ord == 1 ? part1 : part2;
    const int roff = ord == 1 ? 1280 : 2816;
    gemm_core<2>(sb, SEQ, vwT, SEQ, op, DEMB, ord == 0 ? bc : nullptr,
                 bm, bn, ni, kt0, 1.f, lds, roff);
}

// out[1280:] += part1 (+part2 for rows >= 2816). 5632 blocks x 256 thr.
__global__ __launch_bounds__(256) void k_reduce(
        float* __restrict__ out, const float* __restrict__ part1,
        const float* __restrict__ part2) {
    const int idx = (blockIdx.x * 256 + threadIdx.x) * 4;   // f32 idx in region
    float4 o = *(float4*)&out[(size_t)1280 * DEMB + idx];
    float4 p = *(const float4*)&part1[idx];
    o.x += p.x; o.y += p.y; o.z += p.z; o.w += p.w;
    if (idx >= 1536 * DEMB) {                               // row >= 2816
        float4 q = *(const float4*)&part2[idx - 1536 * DEMB];
        o.x += q.x; o.y += q.y; o.z += q.z; o.w += q.w;
    }
    *(float4*)&out[(size_t)1280 * DEMB + idx] = o;
}

// ---------------------------------------------------------------------------
extern "C" void kernel_launch(void* const* d_in, const int* in_sizes, int n_in,
                              void* d_out, int out_size, void* d_ws, size_t ws_size,
                              hipStream_t stream) {
    const float* x  = (const float*)d_in[0];
    const float* WQ = (const float*)d_in[1];
    const float* WK = (const float*)d_in[2];
    const float* WV = (const float*)d_in[3];
    const float* WO = (const float*)d_in[4];
    const float* bQ = (const float*)d_in[5];
    const float* bK = (const float*)d_in[6];
    const float* bV = (const float*)d_in[7];
    const float* bO = (const float*)d_in[8];
    float* out = (float*)d_out;

    // workspace (~126 MB); vwT aliases {wv16,wot};
    // part1 aliases qk16 (23.1 MB), part2 aliases wqkt (10.5 MB) - both dead.
    char* w = (char*)d_ws;
    f16* qk16 = (f16*)w; w += (size_t)SEQ * 2 * DEMB * 2;     // 33.5 MB
    f16* sb   = (f16*)w; w += (size_t)SEQ * SEQ * 2;          // 33.5 MB
    f16* x16  = (f16*)w; w += (size_t)SEQ * DEMB * 2;         // 16.8 MB
    f16* wqkt = (f16*)w; w += (size_t)2 * DEMB * DEMB * 2;    // 16.8 MB
    f16* wv16 = (f16*)w; w += (size_t)DEMB * DEMB * 2;        //  8.4 MB
    f16* wot  = (f16*)w; w += (size_t)DEMB * DEMB * 2;        //  8.4 MB
    f16* wvoT = (f16*)w; w += (size_t)DEMB * DEMB * 2;        //  8.4 MB
    float* bqk = (float*)w; w += 2 * DEMB * 4;                // 16 KB
    float* bc  = (float*)w; w += DEMB * 4 + 4096;             //  8 KB
    f16* vwT = wv16;                    // [2048][4096], spans wv16+wot
    float* part1 = (float*)qk16;        // rows 1280+: 2816x2048 f32 = 23.1 MB
    float* part2 = (float*)wqkt;        // rows 2816+: 1280x2048 f32 = 10.5 MB

    // prep: cvt + bias copies + weight transposes, one launch
    k_prep<<<15366, 256, 0, stream>>>(x, WV, WQ, WK, WO, bQ, bK, bO,
                                      x16, wv16, wqkt, wot, bqk, bc);

    // Round 1: QK(bm0-7) + WVO + bias partials = 256 blocks
    k_mix1<<<256, 512, 0, stream>>>(x16, wqkt, qk16, bqk, wv16, wot, wvoT,
                                    WO, bV, bc);

    // Round 2: QK(bm8-15) + VW = 256 blocks
    k_mix2<<<256, 512, 0, stream>>>(x16, wqkt, qk16, bqk, wvoT, vwT);

    // scores (triangular, XCD-chunked)
    k_scores<<<136, 512, 0, stream>>>(qk16, sb);

    // softmax: 4096 blocks, small LDS, ~8 blocks/CU, exp cached in LDS
    k_softmax<<<SEQ, 256, 0, stream>>>(sb);

    // PVW: balanced split-K, 32 chunks x 8 = 256 blocks, no atomics
    k_pvw<<<dim3(8, 32), 512, 0, stream>>>(sb, vwT, out, bc, part1, part2);

    // fold partials into rows 1280+
    k_reduce<<<5632, 256, 0, stream>>>(out, part1, part2);
}